// Round 3
// baseline (681.732 us; speedup 1.0000x reference)
//
#include <hip/hip_runtime.h>
#include <cstdint>
#include <cstddef>

typedef unsigned short u16;
typedef u16 u16x8 __attribute__((ext_vector_type(8)));
typedef __bf16 bf16x8 __attribute__((ext_vector_type(8)));
typedef float f32x4 __attribute__((ext_vector_type(4)));

#define B_ROWS 16384
#define DIM 1024
#define ORDH 512
#define NEXP 7
#define NFUSE 2560  // 512 (ord) + 1024 (res) + 1024 (adapter)

__device__ __forceinline__ u16 f2bf(float f) {
  unsigned u = __builtin_bit_cast(unsigned, f);
  u += 0x7FFFu + ((u >> 16) & 1u);  // RNE
  return (u16)(u >> 16);
}
__device__ __forceinline__ float bf2f(u16 h) {
  return __builtin_bit_cast(float, ((unsigned)h) << 16);
}

// async global->LDS, 16B per lane (global_load_lds_dwordx4)
typedef __attribute__((address_space(1))) const void gas_void;
typedef __attribute__((address_space(3))) void las_void;
__device__ __forceinline__ void gload16(const void* g, void* l) {
  __builtin_amdgcn_global_load_lds((gas_void*)g, (las_void*)l, 16, 0, 0);
}

// x fp32 -> bf16 hi + lo (x ~= hi + lo to ~2^-17 rel); also zeroes gcnt.
__global__ __launch_bounds__(256) void convert_x_kernel(
    const float4* __restrict__ x, ushort4* __restrict__ xh,
    ushort4* __restrict__ xl, int* __restrict__ gcnt) {
  if (blockIdx.x == 0 && threadIdx.x < NEXP) gcnt[threadIdx.x] = 0;
  const int i = blockIdx.x * 256 + threadIdx.x;
  float4 v = x[i];
  ushort4 h, l;
  h.x = f2bf(v.x); l.x = f2bf(v.x - bf2f(h.x));
  h.y = f2bf(v.y); l.y = f2bf(v.y - bf2f(h.y));
  h.z = f2bf(v.z); l.z = f2bf(v.z - bf2f(h.z));
  h.w = f2bf(v.w); l.w = f2bf(v.w - bf2f(h.w));
  xh[i] = h; xl[i] = l;
}

// W [K][N] f32 -> WT [N][K] bf16 (hi, optional lo). grid z = expert batch.
__global__ __launch_bounds__(256) void transpose_kernel(
    const float* __restrict__ W, u16* __restrict__ WTh, u16* __restrict__ WTl,
    int K, int N) {
  __shared__ float tile[32][33];
  const int bk = blockIdx.y * 32, bn = blockIdx.x * 32;
  const int tx = threadIdx.x & 31, ty = threadIdx.x >> 5;  // 32 x 8
  const size_t zoff = (size_t)blockIdx.z * K * N;
#pragma unroll
  for (int r = 0; r < 32; r += 8)
    tile[ty + r][tx] = W[zoff + (size_t)(bk + ty + r) * N + (bn + tx)];
  __syncthreads();
#pragma unroll
  for (int r = 0; r < 32; r += 8) {
    const float v = tile[tx][ty + r];
    const size_t o = zoff + (size_t)(bn + ty + r) * K + (bk + tx);
    const u16 h = f2bf(v);
    WTh[o] = h;
    if (WTl) WTl[o] = f2bf(v - bf2f(h));
  }
}

// ---------------------------------------------------------------------------
// Shared GEMM core: 128x128x32 tile, 4 waves (2x2), 4x4 mfma 16x16x32.
// BK=32 -> 16KB/buffer -> 32KB LDS total -> 4+ blocks/CU (TLP for latency)
// while keeping 1-deep prefetch + counted s_waitcnt vmcnt(4) (never drain).
// T2 swizzle for 64B rows: chunk ^= (row>>1)&3, both-sides (pre-swizzled
// global source + swizzled ds_read; LDS dest stays linear per gload_lds HW).
// Multi-pass: flat tile sequence across npass (A,B) pairs, acc carried.
// ---------------------------------------------------------------------------
__device__ __forceinline__ void gemm_loop(
    const u16* __restrict__ aP0, const u16* __restrict__ bP0,
    const u16* __restrict__ aP1, const u16* __restrict__ bP1,
    const u16* __restrict__ aP2, const u16* __restrict__ bP2,
    int npass, int K, int m0, int n0, u16* SM, int tid, f32x4 (&acc)[4][4]) {
  const int lane = tid & 63;
  const int w = tid >> 6;
  const int wm = w >> 1, wn = w & 1;
  const int sRow = tid >> 2, sSlot = tid & 3;  // 64 rows x 4 chunks(16B)
  const int fsw = (sRow >> 1) & 3;
  const int ldsOff = sRow * 32 + sSlot * 8;
  const size_t aOff = (size_t)(m0 + sRow) * K + ((sSlot ^ fsw) * 8);
  const size_t bOff = (size_t)(n0 + sRow) * K + ((sSlot ^ fsw) * 8);
  const u16* aCur = aP0 + aOff;
  const u16* bCur = bP0 + bOff;
  int sp = 0, sk = 0;  // next tile to stage
  auto stageNext = [&](int b) {
    u16* d = SM + b * 8192 + ldsOff;
    const u16* as = aCur + sk;
    const u16* bs = bCur + sk;
#pragma unroll
    for (int r = 0; r < 2; ++r) {
      gload16(as + (size_t)(r * 64) * K, d + r * 2048);
      gload16(bs + (size_t)(r * 64) * K, d + 4096 + r * 2048);
    }
    sk += 32;
    if (sk == K) {
      sk = 0; ++sp;
      if (sp == 1) { aCur = aP1 + aOff; bCur = bP1 + bOff; }
      else         { aCur = aP2 + aOff; bCur = bP2 + bOff; }
    }
  };

  const int ntiles = npass * (K >> 5);
  stageNext(0);
  int cur = 0;
  const int cA = lane >> 4;
  const int colO = (cA ^ ((lane >> 1) & 3)) * 8;  // swizzled read chunk
  for (int ti = 0; ti < ntiles; ++ti) {
    if (ti + 1 < ntiles) {
      stageNext(cur ^ 1);
      // wait for CURRENT buffer's 4 loads (keep the 4 just-issued in flight)
      asm volatile("s_waitcnt vmcnt(4)\n\ts_barrier" ::: "memory");
    } else {
      asm volatile("s_waitcnt vmcnt(0)\n\ts_barrier" ::: "memory");
    }
    const u16* As = SM + cur * 8192;
    const u16* Bs = As + 4096;
    bf16x8 af[4], bfr[4];
#pragma unroll
    for (int t = 0; t < 4; ++t) {
      const int rowA = wm * 64 + t * 16 + (lane & 15);
      af[t] = __builtin_bit_cast(bf16x8, *(const u16x8*)&As[rowA * 32 + colO]);
      const int rowB = wn * 64 + t * 16 + (lane & 15);
      bfr[t] = __builtin_bit_cast(bf16x8, *(const u16x8*)&Bs[rowB * 32 + colO]);
    }
#pragma unroll
    for (int mt = 0; mt < 4; ++mt)
#pragma unroll
      for (int nt = 0; nt < 4; ++nt)
        acc[mt][nt] = __builtin_amdgcn_mfma_f32_16x16x32_bf16(
            af[mt], bfr[nt], acc[mt][nt], 0, 0, 0);
    // all waves done reading buf[cur] before next iteration overwrites it
    asm volatile("s_barrier" ::: "memory");
    cur ^= 1;
  }
}

// bt GEMM. fp32 mode (outF != null, biasF/ldoF) or fused bf16 col-routed mode
// (o0: cols [0,512) ldo 512; o1: [512,1536) ldo 1024; o2: [1536,2560) ldo 1024)
__global__ __launch_bounds__(256, 4) void mgemm_bt_kernel(
    const u16* __restrict__ A0, const u16* __restrict__ B0,
    const u16* __restrict__ A1, const u16* __restrict__ B1,
    const u16* __restrict__ A2, const u16* __restrict__ B2,
    int npass, int K,
    float* __restrict__ outF, const float* __restrict__ biasF, int ldoF,
    u16* __restrict__ o0, u16* __restrict__ o1, u16* __restrict__ o2,
    const float* __restrict__ b0, const float* __restrict__ b1,
    const float* __restrict__ b2) {
  __shared__ __attribute__((aligned(16))) u16 SM[2 * 8192];
  const int tid = threadIdx.x;
  const int lane = tid & 63;
  const int w = tid >> 6;
  const int wm = w >> 1, wn = w & 1;
  // XCD-aware bijective swizzle (nwg % 8 == 0 for all our grids)
  const unsigned nwg = gridDim.x * gridDim.y;
  const unsigned wgid = blockIdx.y * gridDim.x + blockIdx.x;
  const unsigned swz = (wgid & 7u) * (nwg >> 3) + (wgid >> 3);
  const int m0 = (int)(swz / gridDim.x) * 128;
  const int n0 = (int)(swz % gridDim.x) * 128;

  f32x4 acc[4][4] = {};
  gemm_loop(A0, B0, A1, B1, A2, B2, npass, K, m0, n0, SM, tid, acc);

  const int q = lane >> 4, cl = lane & 15;
#pragma unroll
  for (int nt = 0; nt < 4; ++nt) {
    const int col = n0 + wn * 64 + nt * 16 + cl;
    if (outF) {
      const float bv = biasF[col];
#pragma unroll
      for (int mt = 0; mt < 4; ++mt)
#pragma unroll
        for (int i = 0; i < 4; ++i) {
          const int row = m0 + wm * 64 + mt * 16 + q * 4 + i;
          float v = acc[mt][nt][i] + bv;
          outF[(size_t)row * ldoF + col] = v > 0.f ? v : 0.f;
        }
    } else {
      u16* ob; const float* bp; int lc, ld;
      if (col < ORDH)            { ob = o0; bp = b0; lc = col;               ld = ORDH; }
      else if (col < ORDH + DIM) { ob = o1; bp = b1; lc = col - ORDH;        ld = DIM; }
      else                       { ob = o2; bp = b2; lc = col - (ORDH + DIM); ld = DIM; }
      const float bv = bp[lc];
#pragma unroll
      for (int mt = 0; mt < 4; ++mt)
#pragma unroll
        for (int i = 0; i < 4; ++i) {
          const int row = m0 + wm * 64 + mt * 16 + q * 4 + i;
          float v = acc[mt][nt][i] + bv;
          v = v > 0.f ? v : 0.f;
          ob[(size_t)row * ld + lc] = f2bf(v);
        }
    }
  }
}

// expert-segmented GEMM: rows [off[e]+t0, off[e]+cnt[e]); optional A-row gather
// through perm[] (folds the permute kernel into the staging source address).
__global__ __launch_bounds__(256, 4) void mgemm_expert_kernel(
    const u16* __restrict__ Abuf, const u16* __restrict__ Wall,
    const float* __restrict__ biasAll, const int* __restrict__ off,
    const int* __restrict__ cnt, const int* __restrict__ perm, int usePerm,
    u16* __restrict__ outH) {
  __shared__ __attribute__((aligned(16))) u16 SM[2 * 8192];
  const int e = blockIdx.z;
  const int myCnt = cnt[e];
  const int t0 = blockIdx.y * 128;
  if (t0 >= myCnt) return;  // uniform per block (before any barrier)
  const int base = off[e];
  const int m0 = base + t0;
  const int mEnd = base + myCnt;
  const u16* Bp = Wall + (size_t)e * DIM * DIM;
  const float* bias = biasAll + (size_t)e * DIM;

  const int tid = threadIdx.x;
  const int lane = tid & 63;
  const int w = tid >> 6;
  const int wm = w >> 1, wn = w & 1;
  const int n0 = blockIdx.x * 128;
  const int sRow = tid >> 2, sSlot = tid & 3;
  const int fsw = (sRow >> 1) & 3;
  const int ldsOff = sRow * 32 + sSlot * 8;
  const int swzC = (sSlot ^ fsw) * 8;  // pre-swizzled source chunk

  const u16* aSrc[2];
#pragma unroll
  for (int r = 0; r < 2; ++r) {
    int ar = m0 + r * 64 + sRow;
    if (ar > B_ROWS - 1) ar = B_ROWS - 1;  // clamp; masked at store
    const int gr = usePerm ? perm[ar] : ar;
    aSrc[r] = Abuf + (size_t)gr * DIM + swzC;
  }
  const u16* bSrc = Bp + (size_t)(n0 + sRow) * DIM + swzC;

  int sk = 0;
  auto stageNext = [&](int b) {
    u16* d = SM + b * 8192 + ldsOff;
#pragma unroll
    for (int r = 0; r < 2; ++r) {
      gload16(aSrc[r] + sk, d + r * 2048);
      gload16(bSrc + (size_t)(r * 64) * DIM + sk, d + 4096 + r * 2048);
    }
    sk += 32;
  };

  f32x4 acc[4][4] = {};
  const int ntiles = DIM >> 5;
  stageNext(0);
  int cur = 0;
  const int cA = lane >> 4;
  const int colO = (cA ^ ((lane >> 1) & 3)) * 8;
  for (int ti = 0; ti < ntiles; ++ti) {
    if (ti + 1 < ntiles) {
      stageNext(cur ^ 1);
      asm volatile("s_waitcnt vmcnt(4)\n\ts_barrier" ::: "memory");
    } else {
      asm volatile("s_waitcnt vmcnt(0)\n\ts_barrier" ::: "memory");
    }
    const u16* As = SM + cur * 8192;
    const u16* Bs = As + 4096;
    bf16x8 af[4], bfr[4];
#pragma unroll
    for (int t = 0; t < 4; ++t) {
      const int rowA = wm * 64 + t * 16 + (lane & 15);
      af[t] = __builtin_bit_cast(bf16x8, *(const u16x8*)&As[rowA * 32 + colO]);
      const int rowB = wn * 64 + t * 16 + (lane & 15);
      bfr[t] = __builtin_bit_cast(bf16x8, *(const u16x8*)&Bs[rowB * 32 + colO]);
    }
#pragma unroll
    for (int mt = 0; mt < 4; ++mt)
#pragma unroll
      for (int nt = 0; nt < 4; ++nt)
        acc[mt][nt] = __builtin_amdgcn_mfma_f32_16x16x32_bf16(
            af[mt], bfr[nt], acc[mt][nt], 0, 0, 0);
    asm volatile("s_barrier" ::: "memory");
    cur ^= 1;
  }

  const int q = lane >> 4, cl = lane & 15;
#pragma unroll
  for (int nt = 0; nt < 4; ++nt) {
    const int col = n0 + wn * 64 + nt * 16 + cl;
    const float bv = bias[col];
#pragma unroll
    for (int mt = 0; mt < 4; ++mt) {
#pragma unroll
      for (int i = 0; i < 4; ++i) {
        const int row = m0 + wm * 64 + mt * 16 + q * 4 + i;
        if (row < mEnd) {
          float v = acc[mt][nt][i] + bv;
          v = v > 0.f ? v : 0.f;
          outH[(size_t)row * DIM + col] = f2bf(v);
        }
      }
    }
  }
}

// ---------------------------------------------------------------------------
// heads: one wave per row. OUTPUT fp32. res + ord merged (independent).
// ---------------------------------------------------------------------------
__global__ __launch_bounds__(256) void head_resord_kernel(
    const u16* __restrict__ Y3, const float* __restrict__ Wr2,
    const float* __restrict__ br2, float* __restrict__ resv,
    const u16* __restrict__ Y2, const float* __restrict__ Wo2,
    const float* __restrict__ bo2, float* __restrict__ out) {
  const int lane = threadIdx.x & 63;
  const int r = blockIdx.x * 4 + (threadIdx.x >> 6);
  // res: Y3[r,:] . Wr2
  float s = 0.f;
  for (int it = 0; it < 16; ++it) {
    const int k = it * 64 + lane;
    s += bf2f(Y3[(size_t)r * DIM + k]) * Wr2[k];
  }
  for (int o = 32; o > 0; o >>= 1) s += __shfl_down(s, o);
  if (lane == 0) resv[r] = 0.35f * tanhf(s + br2[0]);
  // ord: Y2[r,:] @ Wo2 [512,6]
  float so[6] = {0, 0, 0, 0, 0, 0};
  for (int it = 0; it < 8; ++it) {
    const int k = it * 64 + lane;
    const float v = bf2f(Y2[(size_t)r * ORDH + k]);
    const float* wr = Wo2 + k * 6;
#pragma unroll
    for (int n = 0; n < 6; ++n) so[n] += v * wr[n];
  }
#pragma unroll
  for (int n = 0; n < 6; ++n) {
    float xv = so[n];
    for (int o = 32; o > 0; o >>= 1) xv += __shfl_down(xv, o);
    so[n] = xv;
  }
  if (lane == 0) {
#pragma unroll
    for (int n = 0; n < 6; ++n) out[(size_t)r * 24 + 7 + n] = so[n] + bo2[n];
  }
}

__global__ __launch_bounds__(256) void head_cls_kernel(
    const float* __restrict__ Y1, const float* __restrict__ Wc2,
    const float* __restrict__ bc2, const float* __restrict__ resv,
    float* __restrict__ out, int* __restrict__ size_idx, int* __restrict__ gcnt) {
  __shared__ int lcnt[NEXP];
  const int tid = threadIdx.x;
  if (tid < NEXP) lcnt[tid] = 0;
  __syncthreads();
  const int lane = tid & 63;
  const int r = blockIdx.x * 4 + (tid >> 6);
  float s[7] = {0, 0, 0, 0, 0, 0, 0};
  for (int it = 0; it < 16; ++it) {
    const int k = it * 64 + lane;
    const float v = Y1[(size_t)r * DIM + k];
    const float* wr = Wc2 + k * 7;
#pragma unroll
    for (int n = 0; n < 7; ++n) s[n] += v * wr[n];
  }
#pragma unroll
  for (int n = 0; n < 7; ++n) {
    float xv = s[n];
    for (int o = 32; o > 0; o >>= 1) xv += __shfl_down(xv, o);
    s[n] = xv;
  }
  if (lane == 0) {
    float lg[7], p[7];
    float m = -1e30f;
    int ai = 0;
#pragma unroll
    for (int n = 0; n < 7; ++n) {
      lg[n] = s[n] + bc2[n];
      if (lg[n] > m) { m = lg[n]; ai = n; }  // first max == np.argmax
    }
    float es = 0.f;
#pragma unroll
    for (int n = 0; n < 7; ++n) { p[n] = expf(lg[n] - m); es += p[n]; }
    const float inv = 1.f / es;
    float expect = 0.f;
#pragma unroll
    for (int n = 0; n < 7; ++n) { p[n] *= inv; expect += p[n] * (n * (1.f / 6.f)); }
    float reg = expect + resv[r];
    reg = fminf(fmaxf(reg, 0.f), 1.f);
    float* orow = out + (size_t)r * 24;
#pragma unroll
    for (int n = 0; n < 7; ++n) orow[n] = lg[n];
    orow[13] = reg;
#pragma unroll
    for (int n = 0; n < 7; ++n) orow[14 + n] = p[n];
    size_idx[r] = ai;
    atomicAdd(&lcnt[ai], 1);
  }
  __syncthreads();
  if (tid < NEXP && lcnt[tid] > 0) atomicAdd(&gcnt[tid], lcnt[tid]);
}

__global__ void scan_kernel(const int* __restrict__ gcnt, int* __restrict__ off,
                            int* __restrict__ cursor) {
  if (threadIdx.x == 0) {
    int a = 0;
    for (int e = 0; e < NEXP; ++e) { off[e] = a; cursor[e] = a; a += gcnt[e]; }
    off[NEXP] = a;
  }
}

__global__ __launch_bounds__(256) void scatter_kernel(
    const int* __restrict__ size_idx, int* __restrict__ cursor,
    int* __restrict__ perm) {
  __shared__ int lcnt[NEXP];
  __shared__ int lbase[NEXP];
  const int tid = threadIdx.x;
  if (tid < NEXP) lcnt[tid] = 0;
  __syncthreads();
  const int r = blockIdx.x * 256 + tid;
  const int e = size_idx[r];
  const int lp = atomicAdd(&lcnt[e], 1);
  __syncthreads();
  if (tid < NEXP && lcnt[tid] > 0) lbase[tid] = atomicAdd(&cursor[tid], lcnt[tid]);
  __syncthreads();
  perm[lbase[e] + lp] = r;
}

__global__ __launch_bounds__(256) void head_dl_kernel(
    const u16* __restrict__ H2p, const float* __restrict__ We3,
    const float* __restrict__ be3, const int* __restrict__ off,
    const int* __restrict__ perm, float* __restrict__ out) {
  const int lane = threadIdx.x & 63;
  const int i = blockIdx.x * 4 + (threadIdx.x >> 6);
  int e = 0;
#pragma unroll
  for (int t = 1; t < NEXP; ++t)
    if (i >= off[t]) e = t;
  const float* W = We3 + (size_t)e * DIM * 3;
  float s0 = 0.f, s1 = 0.f, s2 = 0.f;
  for (int it = 0; it < 16; ++it) {
    const int k = it * 64 + lane;
    const float v = bf2f(H2p[(size_t)i * DIM + k]);
    s0 += v * W[k * 3 + 0];
    s1 += v * W[k * 3 + 1];
    s2 += v * W[k * 3 + 2];
  }
  for (int o = 32; o > 0; o >>= 1) {
    s0 += __shfl_down(s0, o);
    s1 += __shfl_down(s1, o);
    s2 += __shfl_down(s2, o);
  }
  if (lane == 0) {
    const int r = perm[i];
    float* orow = out + (size_t)r * 24;
    orow[21] = s0 + be3[e * 3 + 0];
    orow[22] = s1 + be3[e * 3 + 1];
    orow[23] = s2 + be3[e * 3 + 2];
  }
}

// ---------------------------------------------------------------------------
extern "C" void kernel_launch(void* const* d_in, const int* in_sizes, int n_in,
                              void* d_out, int out_size, void* d_ws, size_t ws_size,
                              hipStream_t stream) {
  (void)in_sizes; (void)n_in; (void)out_size; (void)ws_size;
  const float* x   = (const float*)d_in[0];
  const float* Wc1 = (const float*)d_in[1];
  const float* bc1 = (const float*)d_in[2];
  const float* Wc2 = (const float*)d_in[3];
  const float* bc2 = (const float*)d_in[4];
  const float* Wo1 = (const float*)d_in[5];
  const float* bo1 = (const float*)d_in[6];
  const float* Wo2 = (const float*)d_in[7];
  const float* bo2 = (const float*)d_in[8];
  const float* Wr1 = (const float*)d_in[9];
  const float* br1 = (const float*)d_in[10];
  const float* Wr2 = (const float*)d_in[11];
  const float* br2 = (const float*)d_in[12];
  const float* Wa  = (const float*)d_in[13];
  const float* ba  = (const float*)d_in[14];
  const float* We1 = (const float*)d_in[15];
  const float* be1 = (const float*)d_in[16];
  const float* We2 = (const float*)d_in[17];
  const float* be2 = (const float*)d_in[18];
  const float* We3 = (const float*)d_in[19];
  const float* be3 = (const float*)d_in[20];
  float* out = (float*)d_out;  // fp32 output

  char* p = (char*)d_ws;
  auto carve = [&](size_t bytes) {
    char* r = p;
    p += (bytes + 255) & ~(size_t)255;
    return r;
  };
  u16* xh   = (u16*)carve((size_t)B_ROWS * DIM * 2);       // 32MB
  u16* xl   = (u16*)carve((size_t)B_ROWS * DIM * 2);       // 32MB
  u16* Tc1h = (u16*)carve((size_t)DIM * DIM * 2);          // 2MB
  u16* Tc1l = (u16*)carve((size_t)DIM * DIM * 2);          // 2MB
  u16* Tall = (u16*)carve((size_t)NFUSE * DIM * 2);        // 5MB: To1|Tr1|Ta
  u16* Te1  = (u16*)carve((size_t)NEXP * DIM * DIM * 2);   // 14MB
  u16* Te2  = (u16*)carve((size_t)NEXP * DIM * DIM * 2);   // 14MB
  u16* Y3   = (u16*)carve((size_t)B_ROWS * DIM * 2);       // 32MB (res hidden)
  u16* Y2   = (u16*)carve((size_t)B_ROWS * ORDH * 2);      // 16MB (ord hidden)
  carve((size_t)16 << 20);                                 // 16MB pad (tail of Y1)
  u16* DF   = (u16*)carve((size_t)B_ROWS * DIM * 2);       // 32MB (adapter out)
  float* resv = (float*)carve((size_t)B_ROWS * 4);
  int* size_idx = (int*)carve((size_t)B_ROWS * 4);
  int* perm   = (int*)carve((size_t)B_ROWS * 4);
  int* gcnt   = (int*)carve(256);
  int* off    = (int*)carve(256);
  int* cursor = (int*)carve(256);
  // aliases over dead intervals (stream-ordered):
  float* Y1 = (float*)Y3;  // 64MB = Y3(32)+Y2(16)+pad(16); dead after their heads
  u16* H1p = Y3;           // Y1 dead after head_cls
  u16* H2p = DF;           // DF dead after expert1 (gathered read)
  u16* To1 = Tall;                          // fused B rows [0,512)
  u16* Tr1 = Tall + (size_t)ORDH * DIM;     // rows [512,1536)
  u16* Ta  = Tall + (size_t)(ORDH + DIM) * DIM;  // rows [1536,2560)

  dim3 blk(256);
  convert_x_kernel<<<dim3(B_ROWS * DIM / 4 / 256), blk, 0, stream>>>(
      (const float4*)x, (ushort4*)xh, (ushort4*)xl, gcnt);
  transpose_kernel<<<dim3(32, 32, 1), blk, 0, stream>>>(Wc1, Tc1h, Tc1l, DIM, DIM);
  transpose_kernel<<<dim3(16, 32, 1), blk, 0, stream>>>(Wo1, To1, (u16*)nullptr, DIM, ORDH);
  transpose_kernel<<<dim3(32, 32, 1), blk, 0, stream>>>(Wr1, Tr1, (u16*)nullptr, DIM, DIM);
  transpose_kernel<<<dim3(32, 32, 1), blk, 0, stream>>>(Wa, Ta, (u16*)nullptr, DIM, DIM);
  transpose_kernel<<<dim3(32, 32, NEXP), blk, 0, stream>>>(We1, Te1, (u16*)nullptr, DIM, DIM);
  transpose_kernel<<<dim3(32, 32, NEXP), blk, 0, stream>>>(We2, Te2, (u16*)nullptr, DIM, DIM);

  // fused ord+res+adapter hidden GEMM: xh [16384,1024] x Tall^T [2560,1024]
  mgemm_bt_kernel<<<dim3(NFUSE / 128, B_ROWS / 128), blk, 0, stream>>>(
      xh, Tall, xh, Tall, xh, Tall, 1, DIM,
      (float*)nullptr, (const float*)nullptr, 0,
      Y2, Y3, DF, bo1, br1, ba);
  head_resord_kernel<<<dim3(B_ROWS / 4), blk, 0, stream>>>(
      Y3, Wr2, br2, resv, Y2, Wo2, bo2, out);

  // cls hidden: 3-pass hi/lo MFMA -> fp32 Y1 (route-faithful)
  mgemm_bt_kernel<<<dim3(DIM / 128, B_ROWS / 128), blk, 0, stream>>>(
      xh, Tc1h, xh, Tc1l, xl, Tc1h, 3, DIM,
      Y1, bc1, DIM,
      (u16*)nullptr, (u16*)nullptr, (u16*)nullptr,
      (const float*)nullptr, (const float*)nullptr, (const float*)nullptr);
  head_cls_kernel<<<dim3(B_ROWS / 4), blk, 0, stream>>>(Y1, Wc2, bc2, resv, out,
                                                        size_idx, gcnt);
  scan_kernel<<<dim3(1), dim3(64), 0, stream>>>(gcnt, off, cursor);
  scatter_kernel<<<dim3(B_ROWS / 256), blk, 0, stream>>>(size_idx, cursor, perm);

  // expert1 gathers A rows through perm (permute kernel folded in)
  mgemm_expert_kernel<<<dim3(DIM / 128, B_ROWS / 128, NEXP), blk, 0, stream>>>(
      DF, Te1, be1, off, gcnt, perm, 1, H1p);
  mgemm_expert_kernel<<<dim3(DIM / 128, B_ROWS / 128, NEXP), blk, 0, stream>>>(
      H1p, Te2, be2, off, gcnt, perm, 0, H2p);
  head_dl_kernel<<<dim3(B_ROWS / 4), blk, 0, stream>>>(H2p, We3, be3, off, perm, out);
}

// Round 4
// 640.541 us; speedup vs baseline: 1.0643x; 1.0643x over previous
//
#include <hip/hip_runtime.h>
#include <cstdint>
#include <cstddef>

typedef unsigned short u16;
typedef u16 u16x8 __attribute__((ext_vector_type(8)));
typedef __bf16 bf16x8 __attribute__((ext_vector_type(8)));
typedef float f32x4 __attribute__((ext_vector_type(4)));

#define B_ROWS 16384
#define DIM 1024
#define ORDH 512
#define NEXP 7
#define NFUSE 2560  // 512 (ord) + 1024 (res) + 1024 (adapter)

__device__ __forceinline__ u16 f2bf(float f) {
  unsigned u = __builtin_bit_cast(unsigned, f);
  u += 0x7FFFu + ((u >> 16) & 1u);  // RNE
  return (u16)(u >> 16);
}
__device__ __forceinline__ float bf2f(u16 h) {
  return __builtin_bit_cast(float, ((unsigned)h) << 16);
}

// async global->LDS, 16B per lane (global_load_lds_dwordx4)
typedef __attribute__((address_space(1))) const void gas_void;
typedef __attribute__((address_space(3))) void las_void;
__device__ __forceinline__ void gload16(const void* g, void* l) {
  __builtin_amdgcn_global_load_lds((gas_void*)g, (las_void*)l, 16, 0, 0);
}

// x fp32 -> bf16 hi + lo; also zeroes gcnt + cursor (replaces init/scan prep).
__global__ __launch_bounds__(256) void convert_x_kernel(
    const float4* __restrict__ x, ushort4* __restrict__ xh,
    ushort4* __restrict__ xl, int* __restrict__ gcnt, int* __restrict__ cursor) {
  if (blockIdx.x == 0 && threadIdx.x < 2 * NEXP) {
    if (threadIdx.x < NEXP) gcnt[threadIdx.x] = 0;
    else cursor[threadIdx.x - NEXP] = 0;
  }
  const int i = blockIdx.x * 256 + threadIdx.x;
  float4 v = x[i];
  ushort4 h, l;
  h.x = f2bf(v.x); l.x = f2bf(v.x - bf2f(h.x));
  h.y = f2bf(v.y); l.y = f2bf(v.y - bf2f(h.y));
  h.z = f2bf(v.z); l.z = f2bf(v.z - bf2f(h.z));
  h.w = f2bf(v.w); l.w = f2bf(v.w - bf2f(h.w));
  xh[i] = h; xl[i] = l;
}

// ALL weight transposes in one launch. W [K][N] f32 -> WT [N][K] bf16.
// flat grid decode: Wc1(1024) | Wo1(512) | Wr1(1024) | Wa(1024) |
//                   We1(7x1024) | We2(7x1024)  = 17920 blocks
__global__ __launch_bounds__(256) void transpose_all_kernel(
    const float* __restrict__ Wc1, u16* __restrict__ Tc1h, u16* __restrict__ Tc1l,
    const float* __restrict__ Wo1, u16* __restrict__ To1,
    const float* __restrict__ Wr1, u16* __restrict__ Tr1,
    const float* __restrict__ Wa,  u16* __restrict__ Ta,
    const float* __restrict__ We1, u16* __restrict__ Te1,
    const float* __restrict__ We2, u16* __restrict__ Te2) {
  __shared__ float tile[32][33];
  int bid = blockIdx.x;
  const float* W; u16* H; u16* L = nullptr;
  int N = 1024, bx, by;
  size_t zoff = 0;
  if (bid < 1024)      { W = Wc1; H = Tc1h; L = Tc1l; bx = bid & 31; by = bid >> 5; }
  else if (bid < 1536) { bid -= 1024; W = Wo1; H = To1; N = 512; bx = bid & 15; by = bid >> 4; }
  else if (bid < 2560) { bid -= 1536; W = Wr1; H = Tr1; bx = bid & 31; by = bid >> 5; }
  else if (bid < 3584) { bid -= 2560; W = Wa; H = Ta; bx = bid & 31; by = bid >> 5; }
  else if (bid < 10752){ bid -= 3584; W = We1; H = Te1;
                         zoff = (size_t)(bid >> 10) * DIM * DIM; bid &= 1023;
                         bx = bid & 31; by = bid >> 5; }
  else                 { bid -= 10752; W = We2; H = Te2;
                         zoff = (size_t)(bid >> 10) * DIM * DIM; bid &= 1023;
                         bx = bid & 31; by = bid >> 5; }
  const int K = 1024;
  const int bk = by * 32, bn = bx * 32;
  const int tx = threadIdx.x & 31, ty = threadIdx.x >> 5;  // 32 x 8
#pragma unroll
  for (int r = 0; r < 32; r += 8)
    tile[ty + r][tx] = W[zoff + (size_t)(bk + ty + r) * N + (bn + tx)];
  __syncthreads();
#pragma unroll
  for (int r = 0; r < 32; r += 8) {
    const float v = tile[tx][ty + r];
    const size_t o = zoff + (size_t)(bn + ty + r) * K + (bk + tx);
    const u16 h = f2bf(v);
    H[o] = h;
    if (L) L[o] = f2bf(v - bf2f(h));
  }
}

// ---------------------------------------------------------------------------
// Shared GEMM core (R2 structure, proven): 128x128x64 tile, 4 waves (2x2),
// 4x4 mfma 16x16x32. global_load_lds width-16 into LINEAR LDS; T2 both-sides
// swizzle (chunk ^= row&7); double-buffer 2x32KB; counted s_waitcnt vmcnt(8)
// (never drain in main loop); T5 setprio around MFMA cluster.
// ---------------------------------------------------------------------------
__device__ __forceinline__ void gemm_loop(
    const u16* __restrict__ aP0, const u16* __restrict__ bP0,
    const u16* __restrict__ aP1, const u16* __restrict__ bP1,
    const u16* __restrict__ aP2, const u16* __restrict__ bP2,
    int npass, int K, int m0, int n0, u16* SM, int tid, f32x4 (&acc)[4][4]) {
  const int lane = tid & 63;
  const int w = tid >> 6;
  const int wm = w >> 1, wn = w & 1;
  const int sRow = tid >> 3, sSlot = tid & 7;  // 32 rows x 8 chunks(16B)
  const int ldsOff = sRow * 64 + sSlot * 8;
  const size_t aOff = (size_t)(m0 + sRow) * K + ((sSlot ^ (sRow & 7)) * 8);
  const size_t bOff = (size_t)(n0 + sRow) * K + ((sSlot ^ (sRow & 7)) * 8);
  const u16* aCur = aP0 + aOff;
  const u16* bCur = bP0 + bOff;
  int sp = 0, sk = 0;  // next tile to stage
  auto stageNext = [&](int b) {
    u16* d = SM + b * 16384 + ldsOff;
    const u16* as = aCur + sk;
    const u16* bs = bCur + sk;
#pragma unroll
    for (int r = 0; r < 4; ++r) {
      gload16(as + (size_t)(r * 32) * K, d + r * 32 * 64);
      gload16(bs + (size_t)(r * 32) * K, d + 8192 + r * 32 * 64);
    }
    sk += 64;
    if (sk == K) {
      sk = 0; ++sp;
      if (sp == 1) { aCur = aP1 + aOff; bCur = bP1 + bOff; }
      else         { aCur = aP2 + aOff; bCur = bP2 + bOff; }
    }
  };

  const int ntiles = npass * (K >> 6);
  stageNext(0);
  int cur = 0;
  for (int ti = 0; ti < ntiles; ++ti) {
    if (ti + 1 < ntiles) {
      stageNext(cur ^ 1);
      // wait for CURRENT buffer's 8 loads (keep the 8 just-issued in flight)
      asm volatile("s_waitcnt vmcnt(8)\n\ts_barrier" ::: "memory");
    } else {
      asm volatile("s_waitcnt vmcnt(0)\n\ts_barrier" ::: "memory");
    }
    const u16* As = SM + cur * 16384;
    const u16* Bs = As + 8192;
#pragma unroll
    for (int s = 0; s < 2; ++s) {
      const int cAx = s * 4 + (lane >> 4);
      const int colO = (cAx ^ (lane & 7)) * 8;  // T2 swizzled read chunk
      bf16x8 af[4], bfr[4];
#pragma unroll
      for (int t = 0; t < 4; ++t) {
        const int rowA = wm * 64 + t * 16 + (lane & 15);
        af[t] = __builtin_bit_cast(bf16x8, *(const u16x8*)&As[rowA * 64 + colO]);
        const int rowB = wn * 64 + t * 16 + (lane & 15);
        bfr[t] = __builtin_bit_cast(bf16x8, *(const u16x8*)&Bs[rowB * 64 + colO]);
      }
      __builtin_amdgcn_s_setprio(1);
#pragma unroll
      for (int mt = 0; mt < 4; ++mt)
#pragma unroll
        for (int nt = 0; nt < 4; ++nt)
          acc[mt][nt] = __builtin_amdgcn_mfma_f32_16x16x32_bf16(
              af[mt], bfr[nt], acc[mt][nt], 0, 0, 0);
      __builtin_amdgcn_s_setprio(0);
    }
    // all waves done reading buf[cur] before next iteration overwrites it
    asm volatile("s_barrier" ::: "memory");
    cur ^= 1;
  }
}

// bt GEMM. fp32 mode (outF != null, biasF/ldoF) or fused bf16 col-routed mode
// (o0: cols [0,512) ldo 512; o1: [512,1536) ldo 1024; o2: [1536,2560) ldo 1024)
__global__ __launch_bounds__(256, 2) void mgemm_bt_kernel(
    const u16* __restrict__ A0, const u16* __restrict__ B0,
    const u16* __restrict__ A1, const u16* __restrict__ B1,
    const u16* __restrict__ A2, const u16* __restrict__ B2,
    int npass, int K,
    float* __restrict__ outF, const float* __restrict__ biasF, int ldoF,
    u16* __restrict__ o0, u16* __restrict__ o1, u16* __restrict__ o2,
    const float* __restrict__ b0, const float* __restrict__ b1,
    const float* __restrict__ b2) {
  __shared__ __attribute__((aligned(16))) u16 SM[4 * 128 * 64];
  const int tid = threadIdx.x;
  const int lane = tid & 63;
  const int w = tid >> 6;
  const int wm = w >> 1, wn = w & 1;
  // XCD-aware bijective swizzle (nwg % 8 == 0 for all our grids)
  const unsigned nwg = gridDim.x * gridDim.y;
  const unsigned wgid = blockIdx.y * gridDim.x + blockIdx.x;
  const unsigned swz = (wgid & 7u) * (nwg >> 3) + (wgid >> 3);
  const int m0 = (int)(swz / gridDim.x) * 128;
  const int n0 = (int)(swz % gridDim.x) * 128;

  f32x4 acc[4][4] = {};
  gemm_loop(A0, B0, A1, B1, A2, B2, npass, K, m0, n0, SM, tid, acc);

  const int q = lane >> 4, cl = lane & 15;
#pragma unroll
  for (int nt = 0; nt < 4; ++nt) {
    const int col = n0 + wn * 64 + nt * 16 + cl;
    if (outF) {
      const float bv = biasF[col];
#pragma unroll
      for (int mt = 0; mt < 4; ++mt)
#pragma unroll
        for (int i = 0; i < 4; ++i) {
          const int row = m0 + wm * 64 + mt * 16 + q * 4 + i;
          float v = acc[mt][nt][i] + bv;
          outF[(size_t)row * ldoF + col] = v > 0.f ? v : 0.f;
        }
    } else {
      u16* ob; const float* bp; int lc, ld;
      if (col < ORDH)            { ob = o0; bp = b0; lc = col;               ld = ORDH; }
      else if (col < ORDH + DIM) { ob = o1; bp = b1; lc = col - ORDH;        ld = DIM; }
      else                       { ob = o2; bp = b2; lc = col - (ORDH + DIM); ld = DIM; }
      const float bv = bp[lc];
#pragma unroll
      for (int mt = 0; mt < 4; ++mt)
#pragma unroll
        for (int i = 0; i < 4; ++i) {
          const int row = m0 + wm * 64 + mt * 16 + q * 4 + i;
          float v = acc[mt][nt][i] + bv;
          v = v > 0.f ? v : 0.f;
          ob[(size_t)row * ld + lc] = f2bf(v);
        }
    }
  }
}

// expert-segmented GEMM: rows [base+t0, base+cnt[e]) where base = prefix(gcnt);
// optional A-row gather through perm[] (permute kernel folded into staging).
__global__ __launch_bounds__(256, 2) void mgemm_expert_kernel(
    const u16* __restrict__ Abuf, const u16* __restrict__ Wall,
    const float* __restrict__ biasAll, const int* __restrict__ cnt,
    const int* __restrict__ perm, int usePerm, u16* __restrict__ outH) {
  __shared__ __attribute__((aligned(16))) u16 SM[4 * 128 * 64];
  const int e = blockIdx.z;
  const int myCnt = cnt[e];
  const int t0 = blockIdx.y * 128;
  if (t0 >= myCnt) return;  // uniform per block (before any barrier)
  int base = 0;
  for (int t = 0; t < NEXP; ++t) base += (t < e) ? cnt[t] : 0;
  const int m0 = base + t0;
  const int mEnd = base + myCnt;
  const u16* Bp = Wall + (size_t)e * DIM * DIM;
  const float* bias = biasAll + (size_t)e * DIM;

  const int tid = threadIdx.x;
  const int lane = tid & 63;
  const int w = tid >> 6;
  const int wm = w >> 1, wn = w & 1;
  const int n0 = blockIdx.x * 128;
  const int sRow = tid >> 3, sSlot = tid & 7;
  const int ldsOff = sRow * 64 + sSlot * 8;
  const int swzC = (sSlot ^ (sRow & 7)) * 8;  // pre-swizzled source chunk

  const u16* aSrc[4];
#pragma unroll
  for (int r = 0; r < 4; ++r) {
    int ar = m0 + r * 32 + sRow;
    if (ar > B_ROWS - 1) ar = B_ROWS - 1;  // clamp; masked at store
    const int gr = usePerm ? perm[ar] : ar;
    aSrc[r] = Abuf + (size_t)gr * DIM + swzC;
  }
  const u16* bSrc = Bp + (size_t)(n0 + sRow) * DIM + swzC;

  int sk = 0;
  auto stageNext = [&](int b) {
    u16* d = SM + b * 16384 + ldsOff;
#pragma unroll
    for (int r = 0; r < 4; ++r)
      gload16(aSrc[r] + sk, d + r * 32 * 64);
#pragma unroll
    for (int r = 0; r < 4; ++r)
      gload16(bSrc + (size_t)(r * 32) * DIM + sk, d + 8192 + r * 32 * 64);
    sk += 64;
  };

  f32x4 acc[4][4] = {};
  const int ntiles = DIM >> 6;
  stageNext(0);
  int cur = 0;
  for (int ti = 0; ti < ntiles; ++ti) {
    if (ti + 1 < ntiles) {
      stageNext(cur ^ 1);
      asm volatile("s_waitcnt vmcnt(8)\n\ts_barrier" ::: "memory");
    } else {
      asm volatile("s_waitcnt vmcnt(0)\n\ts_barrier" ::: "memory");
    }
    const u16* As = SM + cur * 16384;
    const u16* Bs = As + 8192;
#pragma unroll
    for (int s = 0; s < 2; ++s) {
      const int cAx = s * 4 + (lane >> 4);
      const int colO = (cAx ^ (lane & 7)) * 8;
      bf16x8 af[4], bfr[4];
#pragma unroll
      for (int t = 0; t < 4; ++t) {
        const int rowA = wm * 64 + t * 16 + (lane & 15);
        af[t] = __builtin_bit_cast(bf16x8, *(const u16x8*)&As[rowA * 64 + colO]);
        const int rowB = wn * 64 + t * 16 + (lane & 15);
        bfr[t] = __builtin_bit_cast(bf16x8, *(const u16x8*)&Bs[rowB * 64 + colO]);
      }
      __builtin_amdgcn_s_setprio(1);
#pragma unroll
      for (int mt = 0; mt < 4; ++mt)
#pragma unroll
        for (int nt = 0; nt < 4; ++nt)
          acc[mt][nt] = __builtin_amdgcn_mfma_f32_16x16x32_bf16(
              af[mt], bfr[nt], acc[mt][nt], 0, 0, 0);
      __builtin_amdgcn_s_setprio(0);
    }
    asm volatile("s_barrier" ::: "memory");
    cur ^= 1;
  }

  const int q = lane >> 4, cl = lane & 15;
#pragma unroll
  for (int nt = 0; nt < 4; ++nt) {
    const int col = n0 + wn * 64 + nt * 16 + cl;
    const float bv = bias[col];
#pragma unroll
    for (int mt = 0; mt < 4; ++mt) {
#pragma unroll
      for (int i = 0; i < 4; ++i) {
        const int row = m0 + wm * 64 + mt * 16 + q * 4 + i;
        if (row < mEnd) {
          float v = acc[mt][nt][i] + bv;
          v = v > 0.f ? v : 0.f;
          outH[(size_t)row * DIM + col] = f2bf(v);
        }
      }
    }
  }
}

// ---------------------------------------------------------------------------
// heads: one wave per row. OUTPUT fp32. res + ord merged (independent).
// ---------------------------------------------------------------------------
__global__ __launch_bounds__(256) void head_resord_kernel(
    const u16* __restrict__ Y3, const float* __restrict__ Wr2,
    const float* __restrict__ br2, float* __restrict__ resv,
    const u16* __restrict__ Y2, const float* __restrict__ Wo2,
    const float* __restrict__ bo2, float* __restrict__ out) {
  const int lane = threadIdx.x & 63;
  const int r = blockIdx.x * 4 + (threadIdx.x >> 6);
  // res: Y3[r,:] . Wr2
  float s = 0.f;
  for (int it = 0; it < 16; ++it) {
    const int k = it * 64 + lane;
    s += bf2f(Y3[(size_t)r * DIM + k]) * Wr2[k];
  }
  for (int o = 32; o > 0; o >>= 1) s += __shfl_down(s, o);
  if (lane == 0) resv[r] = 0.35f * tanhf(s + br2[0]);
  // ord: Y2[r,:] @ Wo2 [512,6]
  float so[6] = {0, 0, 0, 0, 0, 0};
  for (int it = 0; it < 8; ++it) {
    const int k = it * 64 + lane;
    const float v = bf2f(Y2[(size_t)r * ORDH + k]);
    const float* wr = Wo2 + k * 6;
#pragma unroll
    for (int n = 0; n < 6; ++n) so[n] += v * wr[n];
  }
#pragma unroll
  for (int n = 0; n < 6; ++n) {
    float xv = so[n];
    for (int o = 32; o > 0; o >>= 1) xv += __shfl_down(xv, o);
    so[n] = xv;
  }
  if (lane == 0) {
#pragma unroll
    for (int n = 0; n < 6; ++n) out[(size_t)r * 24 + 7 + n] = so[n] + bo2[n];
  }
}

__global__ __launch_bounds__(256) void head_cls_kernel(
    const float* __restrict__ Y1, const float* __restrict__ Wc2,
    const float* __restrict__ bc2, const float* __restrict__ resv,
    float* __restrict__ out, int* __restrict__ size_idx, int* __restrict__ gcnt) {
  __shared__ int lcnt[NEXP];
  const int tid = threadIdx.x;
  if (tid < NEXP) lcnt[tid] = 0;
  __syncthreads();
  const int lane = tid & 63;
  const int r = blockIdx.x * 4 + (tid >> 6);
  float s[7] = {0, 0, 0, 0, 0, 0, 0};
  for (int it = 0; it < 16; ++it) {
    const int k = it * 64 + lane;
    const float v = Y1[(size_t)r * DIM + k];
    const float* wr = Wc2 + k * 7;
#pragma unroll
    for (int n = 0; n < 7; ++n) s[n] += v * wr[n];
  }
#pragma unroll
  for (int n = 0; n < 7; ++n) {
    float xv = s[n];
    for (int o = 32; o > 0; o >>= 1) xv += __shfl_down(xv, o);
    s[n] = xv;
  }
  if (lane == 0) {
    float lg[7], p[7];
    float m = -1e30f;
    int ai = 0;
#pragma unroll
    for (int n = 0; n < 7; ++n) {
      lg[n] = s[n] + bc2[n];
      if (lg[n] > m) { m = lg[n]; ai = n; }  // first max == np.argmax
    }
    float es = 0.f;
#pragma unroll
    for (int n = 0; n < 7; ++n) { p[n] = expf(lg[n] - m); es += p[n]; }
    const float inv = 1.f / es;
    float expect = 0.f;
#pragma unroll
    for (int n = 0; n < 7; ++n) { p[n] *= inv; expect += p[n] * (n * (1.f / 6.f)); }
    float reg = expect + resv[r];
    reg = fminf(fmaxf(reg, 0.f), 1.f);
    float* orow = out + (size_t)r * 24;
#pragma unroll
    for (int n = 0; n < 7; ++n) orow[n] = lg[n];
    orow[13] = reg;
#pragma unroll
    for (int n = 0; n < 7; ++n) orow[14 + n] = p[n];
    size_idx[r] = ai;
    atomicAdd(&lcnt[ai], 1);
  }
  __syncthreads();
  if (tid < NEXP && lcnt[tid] > 0) atomicAdd(&gcnt[tid], lcnt[tid]);
}

// scatter: off computed locally from final gcnt (scan kernel eliminated);
// cursor pre-zeroed in convert_x.
__global__ __launch_bounds__(256) void scatter_kernel(
    const int* __restrict__ size_idx, const int* __restrict__ gcnt,
    int* __restrict__ cursor, int* __restrict__ perm) {
  __shared__ int lcnt[NEXP];
  __shared__ int lbase[NEXP];
  const int tid = threadIdx.x;
  if (tid < NEXP) lcnt[tid] = 0;
  __syncthreads();
  const int r = blockIdx.x * 256 + tid;
  const int e = size_idx[r];
  const int lp = atomicAdd(&lcnt[e], 1);
  __syncthreads();
  if (tid < NEXP && lcnt[tid] > 0) {
    int off = 0;
    for (int t = 0; t < tid; ++t) off += gcnt[t];
    lbase[tid] = off + atomicAdd(&cursor[tid], lcnt[tid]);
  }
  __syncthreads();
  perm[lbase[e] + lp] = r;
}

__global__ __launch_bounds__(256) void head_dl_kernel(
    const u16* __restrict__ H2p, const float* __restrict__ We3,
    const float* __restrict__ be3, const int* __restrict__ gcnt,
    const int* __restrict__ perm, float* __restrict__ out) {
  const int lane = threadIdx.x & 63;
  const int i = blockIdx.x * 4 + (threadIdx.x >> 6);
  int e = 0, acc = 0;
#pragma unroll
  for (int t = 0; t < NEXP - 1; ++t) {
    acc += gcnt[t];
    if (i >= acc) e = t + 1;
  }
  const float* W = We3 + (size_t)e * DIM * 3;
  float s0 = 0.f, s1 = 0.f, s2 = 0.f;
  for (int it = 0; it < 16; ++it) {
    const int k = it * 64 + lane;
    const float v = bf2f(H2p[(size_t)i * DIM + k]);
    s0 += v * W[k * 3 + 0];
    s1 += v * W[k * 3 + 1];
    s2 += v * W[k * 3 + 2];
  }
  for (int o = 32; o > 0; o >>= 1) {
    s0 += __shfl_down(s0, o);
    s1 += __shfl_down(s1, o);
    s2 += __shfl_down(s2, o);
  }
  if (lane == 0) {
    const int r = perm[i];
    float* orow = out + (size_t)r * 24;
    orow[21] = s0 + be3[e * 3 + 0];
    orow[22] = s1 + be3[e * 3 + 1];
    orow[23] = s2 + be3[e * 3 + 2];
  }
}

// ---------------------------------------------------------------------------
extern "C" void kernel_launch(void* const* d_in, const int* in_sizes, int n_in,
                              void* d_out, int out_size, void* d_ws, size_t ws_size,
                              hipStream_t stream) {
  (void)in_sizes; (void)n_in; (void)out_size; (void)ws_size;
  const float* x   = (const float*)d_in[0];
  const float* Wc1 = (const float*)d_in[1];
  const float* bc1 = (const float*)d_in[2];
  const float* Wc2 = (const float*)d_in[3];
  const float* bc2 = (const float*)d_in[4];
  const float* Wo1 = (const float*)d_in[5];
  const float* bo1 = (const float*)d_in[6];
  const float* Wo2 = (const float*)d_in[7];
  const float* bo2 = (const float*)d_in[8];
  const float* Wr1 = (const float*)d_in[9];
  const float* br1 = (const float*)d_in[10];
  const float* Wr2 = (const float*)d_in[11];
  const float* br2 = (const float*)d_in[12];
  const float* Wa  = (const float*)d_in[13];
  const float* ba  = (const float*)d_in[14];
  const float* We1 = (const float*)d_in[15];
  const float* be1 = (const float*)d_in[16];
  const float* We2 = (const float*)d_in[17];
  const float* be2 = (const float*)d_in[18];
  const float* We3 = (const float*)d_in[19];
  const float* be3 = (const float*)d_in[20];
  float* out = (float*)d_out;  // fp32 output

  char* p = (char*)d_ws;
  auto carve = [&](size_t bytes) {
    char* r = p;
    p += (bytes + 255) & ~(size_t)255;
    return r;
  };
  u16* xh   = (u16*)carve((size_t)B_ROWS * DIM * 2);       // 32MB
  u16* xl   = (u16*)carve((size_t)B_ROWS * DIM * 2);       // 32MB
  u16* Tc1h = (u16*)carve((size_t)DIM * DIM * 2);          // 2MB
  u16* Tc1l = (u16*)carve((size_t)DIM * DIM * 2);          // 2MB
  u16* Tall = (u16*)carve((size_t)NFUSE * DIM * 2);        // 5MB: To1|Tr1|Ta
  u16* Te1  = (u16*)carve((size_t)NEXP * DIM * DIM * 2);   // 14MB
  u16* Te2  = (u16*)carve((size_t)NEXP * DIM * DIM * 2);   // 14MB
  u16* Y3   = (u16*)carve((size_t)B_ROWS * DIM * 2);       // 32MB (res hidden)
  u16* Y2   = (u16*)carve((size_t)B_ROWS * ORDH * 2);      // 16MB (ord hidden)
  carve((size_t)16 << 20);                                 // 16MB pad (tail of Y1)
  u16* DF   = (u16*)carve((size_t)B_ROWS * DIM * 2);       // 32MB (adapter out)
  float* resv = (float*)carve((size_t)B_ROWS * 4);
  int* size_idx = (int*)carve((size_t)B_ROWS * 4);
  int* perm   = (int*)carve((size_t)B_ROWS * 4);
  int* gcnt   = (int*)carve(256);
  int* cursor = (int*)carve(256);
  // aliases over dead intervals (stream-ordered):
  float* Y1 = (float*)Y3;  // 64MB = Y3(32)+Y2(16)+pad(16); dead after their heads
  u16* H1p = Y3;           // Y1 dead after head_cls
  u16* H2p = DF;           // DF dead after expert1 (gathered read)
  u16* To1 = Tall;                               // fused B rows [0,512)
  u16* Tr1 = Tall + (size_t)ORDH * DIM;          // rows [512,1536)
  u16* Ta  = Tall + (size_t)(ORDH + DIM) * DIM;  // rows [1536,2560)

  dim3 blk(256);
  convert_x_kernel<<<dim3(B_ROWS * DIM / 4 / 256), blk, 0, stream>>>(
      (const float4*)x, (ushort4*)xh, (ushort4*)xl, gcnt, cursor);
  transpose_all_kernel<<<dim3(17920), blk, 0, stream>>>(
      Wc1, Tc1h, Tc1l, Wo1, To1, Wr1, Tr1, Wa, Ta, We1, Te1, We2, Te2);

  // fused ord+res+adapter hidden GEMM: xh [16384,1024] x Tall^T [2560,1024]
  mgemm_bt_kernel<<<dim3(NFUSE / 128, B_ROWS / 128), blk, 0, stream>>>(
      xh, Tall, xh, Tall, xh, Tall, 1, DIM,
      (float*)nullptr, (const float*)nullptr, 0,
      Y2, Y3, DF, bo1, br1, ba);
  head_resord_kernel<<<dim3(B_ROWS / 4), blk, 0, stream>>>(
      Y3, Wr2, br2, resv, Y2, Wo2, bo2, out);

  // cls hidden: 3-pass hi/lo MFMA -> fp32 Y1 (route-faithful)
  mgemm_bt_kernel<<<dim3(DIM / 128, B_ROWS / 128), blk, 0, stream>>>(
      xh, Tc1h, xh, Tc1l, xl, Tc1h, 3, DIM,
      Y1, bc1, DIM,
      (u16*)nullptr, (u16*)nullptr, (u16*)nullptr,
      (const float*)nullptr, (const float*)nullptr, (const float*)nullptr);
  head_cls_kernel<<<dim3(B_ROWS / 4), blk, 0, stream>>>(Y1, Wc2, bc2, resv, out,
                                                        size_idx, gcnt);
  scatter_kernel<<<dim3(B_ROWS / 256), blk, 0, stream>>>(size_idx, gcnt, cursor, perm);

  // expert1 gathers A rows through perm (permute kernel folded in)
  mgemm_expert_kernel<<<dim3(DIM / 128, B_ROWS / 128, NEXP), blk, 0, stream>>>(
      DF, Te1, be1, gcnt, perm, 1, H1p);
  mgemm_expert_kernel<<<dim3(DIM / 128, B_ROWS / 128, NEXP), blk, 0, stream>>>(
      H1p, Te2, be2, gcnt, perm, 0, H2p);
  head_dl_kernel<<<dim3(B_ROWS / 4), blk, 0, stream>>>(H2p, We3, be3, gcnt, perm, out);
}